// Round 1
// baseline (1553.158 us; speedup 1.0000x reference)
//
#include <hip/hip_runtime.h>
#include <math.h>

// Problem dims (fixed by reference)
constexpr int DXc = 1024;
constexpr int DZc = 1024;
constexpr int LXc = 4096;
constexpr int LZc = 4096;
constexpr int DAc = 1024;   // DATTN
constexpr int DOc = 1024;   // DOUT

// ---------------------------------------------------------------------------
// Generic tiled fp32 GEMM:  C[m,n] = sum_k opA(m,k) * opB(k,n) + bias[m]
//   TA=false: A is (M,K) row-major, access A[m*lda+k]
//   TA=true : A is (K,M) row-major, access A[k*lda+m]   (i.e. C = A^T B form)
//   TB=false: B is (K,N) row-major, access B[k*ldb+n]
//   TB=true : B is (N,K) row-major, access B[n*ldb+k]   (i.e. C = A B^T form)
// Tile: BM=BN=64, BK=16; 256 threads; each thread computes 4x4.
// All dims here are multiples of 64/16 -> no bounds checks.
// ---------------------------------------------------------------------------
template<bool TA, bool TB>
__global__ __launch_bounds__(256)
void gemm_kernel(const float* __restrict__ A, const float* __restrict__ B,
                 const float* __restrict__ bias, float* __restrict__ C,
                 int M, int N, int K, int lda, int ldb, int ldc)
{
    constexpr int BM = 64, BN = 64, BK = 16;
    __shared__ float As[BK][BM + 4];   // +4 pad: keeps 16B alignment, kills conflicts
    __shared__ float Bs[BK][BN + 4];

    const int tid = threadIdx.x;
    const int tx = tid % 16;           // n-direction
    const int ty = tid / 16;           // m-direction
    const int m0 = blockIdx.y * BM;
    const int n0 = blockIdx.x * BN;

    float acc[4][4] = {};

    for (int k0 = 0; k0 < K; k0 += BK) {
        // ---- load A tile -> As[kk][i] ----
        if (TA) {
            // contiguous in m: coalesced
            const int i  = tid % 64;
            const int kb = tid / 64;                   // 0..3
            #pragma unroll
            for (int r = 0; r < 4; ++r) {
                const int kk = kb + r * 4;
                As[kk][i] = A[(size_t)(k0 + kk) * lda + (m0 + i)];
            }
        } else {
            // contiguous in k: 16-float segments per 16 lanes
            const int kk = tid % 16;
            const int ib = tid / 16;                   // 0..15
            #pragma unroll
            for (int r = 0; r < 4; ++r) {
                const int i = ib + r * 16;
                As[kk][i] = A[(size_t)(m0 + i) * lda + (k0 + kk)];
            }
        }
        // ---- load B tile -> Bs[kk][j] ----
        if (!TB) {
            const int j  = tid % 64;
            const int kb = tid / 64;
            #pragma unroll
            for (int r = 0; r < 4; ++r) {
                const int kk = kb + r * 4;
                Bs[kk][j] = B[(size_t)(k0 + kk) * ldb + (n0 + j)];
            }
        } else {
            const int kk = tid % 16;
            const int jb = tid / 16;
            #pragma unroll
            for (int r = 0; r < 4; ++r) {
                const int j = jb + r * 16;
                Bs[kk][j] = B[(size_t)(n0 + j) * ldb + (k0 + kk)];
            }
        }
        __syncthreads();

        #pragma unroll
        for (int kk = 0; kk < BK; ++kk) {
            float a[4], b[4];
            #pragma unroll
            for (int i = 0; i < 4; ++i) a[i] = As[kk][ty * 4 + i];
            #pragma unroll
            for (int j = 0; j < 4; ++j) b[j] = Bs[kk][tx * 4 + j];
            #pragma unroll
            for (int i = 0; i < 4; ++i)
                #pragma unroll
                for (int j = 0; j < 4; ++j)
                    acc[i][j] += a[i] * b[j];
        }
        __syncthreads();
    }

    #pragma unroll
    for (int i = 0; i < 4; ++i) {
        const int m = m0 + ty * 4 + i;
        const float bv = bias ? bias[m] : 0.0f;
        #pragma unroll
        for (int j = 0; j < 4; ++j)
            C[(size_t)m * ldc + (n0 + tx * 4 + j)] = acc[i][j] + bv;
    }
}

// ---------------------------------------------------------------------------
// Row softmax on scoreT (LX rows x LZ cols), with mask applied BEFORE scaling:
//   val = (mask[z,x] ? sT[x,z] : -1000) / 32 ; softmax over z (the row).
// One block (256 threads) per row x; each thread owns 16 z's held in regs.
// mask is (LZ, LX) row-major int32 -> strided read (L3-resident, 64 MB).
// ---------------------------------------------------------------------------
__global__ __launch_bounds__(256)
void softmax_kernel(float* __restrict__ sT, const int* __restrict__ mask)
{
    const int x   = blockIdx.x;
    const int tid = threadIdx.x;
    float* row = sT + (size_t)x * LZc;
    constexpr float scale = 1.0f / 32.0f;   // 1/sqrt(1024)

    float vals[LZc / 256];
    float mx = -1e30f;
    #pragma unroll
    for (int r = 0; r < LZc / 256; ++r) {
        const int z = tid + r * 256;
        float v = mask[(size_t)z * LXc + x] ? row[z] : -1000.0f;
        v *= scale;
        vals[r] = v;
        mx = fmaxf(mx, v);
    }
    // block max reduction
    __shared__ float redmax[4];
    #pragma unroll
    for (int off = 32; off > 0; off >>= 1)
        mx = fmaxf(mx, __shfl_down(mx, off, 64));
    if ((tid & 63) == 0) redmax[tid >> 6] = mx;
    __syncthreads();
    mx = fmaxf(fmaxf(redmax[0], redmax[1]), fmaxf(redmax[2], redmax[3]));

    float sum = 0.0f;
    #pragma unroll
    for (int r = 0; r < LZc / 256; ++r) {
        const float e = __expf(vals[r] - mx);
        vals[r] = e;
        sum += e;
    }
    __shared__ float redsum[4];
    #pragma unroll
    for (int off = 32; off > 0; off >>= 1)
        sum += __shfl_down(sum, off, 64);
    if ((tid & 63) == 0) redsum[tid >> 6] = sum;
    __syncthreads();
    sum = redsum[0] + redsum[1] + redsum[2] + redsum[3];
    const float inv = 1.0f / sum;

    #pragma unroll
    for (int r = 0; r < LZc / 256; ++r)
        row[tid + r * 256] = vals[r] * inv;
}

// ---------------------------------------------------------------------------
extern "C" void kernel_launch(void* const* d_in, const int* in_sizes, int n_in,
                              void* d_out, int out_size, void* d_ws, size_t ws_size,
                              hipStream_t stream)
{
    const float* X    = (const float*)d_in[0];   // (DX, LX)
    const float* Z    = (const float*)d_in[1];   // (DZ, LZ)
    const int*   mask = (const int*)  d_in[2];   // (LZ, LX) 0/1
    const float* Wq   = (const float*)d_in[3];   // (DA, DX)
    const float* bq   = (const float*)d_in[4];   // (DA, 1)
    const float* Wk   = (const float*)d_in[5];   // (DA, DZ)
    const float* bk   = (const float*)d_in[6];
    const float* Wv   = (const float*)d_in[7];   // (DO, DZ)
    const float* bv   = (const float*)d_in[8];
    float* out = (float*)d_out;                  // (DO, LX)

    // workspace layout (fp32): q | k | v | scoreT   = 16+16+16+64 = 112 MB
    float* q  = (float*)d_ws;                    // (DA, LX)
    float* k  = q  + (size_t)DAc * LXc;          // (DA, LZ)
    float* v  = k  + (size_t)DAc * LZc;          // (DO, LZ)
    float* sT = v  + (size_t)DOc * LZc;          // (LX, LZ)  score transposed

    const dim3 blk(256);

    // q = Wq @ X + bq      (NN: M=DA, N=LX, K=DX)
    gemm_kernel<false,false><<<dim3(LXc/64, DAc/64), blk, 0, stream>>>(
        Wq, X, bq, q, DAc, LXc, DXc, DXc, LXc, LXc);
    // k = Wk @ Z + bk
    gemm_kernel<false,false><<<dim3(LZc/64, DAc/64), blk, 0, stream>>>(
        Wk, Z, bk, k, DAc, LZc, DZc, DZc, LZc, LZc);
    // v = Wv @ Z + bv
    gemm_kernel<false,false><<<dim3(LZc/64, DOc/64), blk, 0, stream>>>(
        Wv, Z, bv, v, DOc, LZc, DZc, DZc, LZc, LZc);

    // scoreT[x,z] = sum_d q[d,x] * k[d,z]   (TN: M=LX, N=LZ, K=DA)
    gemm_kernel<true,false><<<dim3(LZc/64, LXc/64), blk, 0, stream>>>(
        q, k, nullptr, sT, LXc, LZc, DAc, LXc, LZc, LZc);

    // masked, scaled softmax over z (rows of sT)
    softmax_kernel<<<dim3(LXc), blk, 0, stream>>>(sT, mask);

    // out[o,x] = sum_z v[o,z] * attnT[x,z]  (NT: M=DO, N=LX, K=LZ)
    gemm_kernel<false,true><<<dim3(LXc/64, DOc/64), blk, 0, stream>>>(
        v, sT, nullptr, out, DOc, LXc, LZc, LZc, LZc, LXc);
}

// Round 2
// 396.322 us; speedup vs baseline: 3.9189x; 3.9189x over previous
//
#include <hip/hip_runtime.h>
#include <hip/hip_bf16.h>
#include <math.h>

constexpr int DXc = 1024;
constexpr int DZc = 1024;
constexpr int LXc = 4096;
constexpr int LZc = 4096;
constexpr int DAc = 1024;   // DATTN
constexpr int DOc = 1024;   // DOUT

typedef __attribute__((ext_vector_type(8))) short bf16x8;   // 8 bf16 = 4 VGPRs
typedef __attribute__((ext_vector_type(4))) float f32x4;

__device__ __forceinline__ ushort f2bf(float f) {
    __hip_bfloat16 h = __float2bfloat16(f);
    return *reinterpret_cast<ushort*>(&h);
}

enum BiasMode { BIAS_NONE, BIAS_M, BIAS_N };

// ---------------------------------------------------------------------------
// bf16 MFMA GEMM:  C[m,n] = sum_k A[m,k]*B[n,k]  (+bias)  (both operands K-major)
// Tile 128x128xBK32, 256 threads = 4 waves in 2x2, each wave 64x64 via 4x4
// MFMA tiles of 16x16x32. Staging via global_load_lds width=16 (contiguous
// LDS layout in lane order -- no padding allowed).
// MASKED (score GEMM only): C masked with mask[n*LX+m] ? v : -1000 before store.
// ---------------------------------------------------------------------------
template<BiasMode BMODE, bool OUT_BF16, bool MASKED>
__global__ __launch_bounds__(256)
void gemm_bt(const ushort* __restrict__ A, const ushort* __restrict__ B,
             const float* __restrict__ bias, const int* __restrict__ mask,
             void* __restrict__ Cv, int M, int N, int K,
             int lda, int ldb, int ldc)
{
    constexpr int BM = 128, BN = 128, BK = 32;
    __shared__ __align__(16) ushort As[BM * BK];   // [m][k] row-major, 8 KB
    __shared__ __align__(16) ushort Bs[BN * BK];   // [n][k] row-major, 8 KB

    const int tid = threadIdx.x;
    const int wv  = tid >> 6;          // wave 0..3
    const int wm  = (wv >> 1) * 64;    // wave m-offset
    const int wn  = (wv & 1) * 64;     // wave n-offset
    const int ln  = tid & 63;
    const int lrow = ln & 15;          // fragment row (m or n within 16)
    const int quad = ln >> 4;          // 0..3

    const int m0 = blockIdx.y * BM;
    const int n0 = blockIdx.x * BN;

    // staging: chunk c (0..511) covers row c>>2, k-seg (c&3)*8 (16B each);
    // issue i uses chunk = i*256 + tid -> LDS dest (i*256 + wv*64)*8 + lane*8
    const int srow = tid >> 2;
    const int sseg = (tid & 3) * 8;
    const ushort* Ag = A + (size_t)(m0 + srow) * lda + sseg;
    const ushort* Bg = B + (size_t)(n0 + srow) * ldb + sseg;
    ushort* AsW = As + wv * 512;       // wave-uniform LDS base (elements)
    ushort* BsW = Bs + wv * 512;

    f32x4 acc[4][4] = {};

    for (int k0 = 0; k0 < K; k0 += BK) {
        __syncthreads();
        __builtin_amdgcn_global_load_lds(
            (const __attribute__((address_space(1))) void*)(Ag + k0),
            (__attribute__((address_space(3))) void*)(AsW), 16, 0, 0);
        __builtin_amdgcn_global_load_lds(
            (const __attribute__((address_space(1))) void*)(Ag + (size_t)64 * lda + k0),
            (__attribute__((address_space(3))) void*)(AsW + 2048), 16, 0, 0);
        __builtin_amdgcn_global_load_lds(
            (const __attribute__((address_space(1))) void*)(Bg + k0),
            (__attribute__((address_space(3))) void*)(BsW), 16, 0, 0);
        __builtin_amdgcn_global_load_lds(
            (const __attribute__((address_space(1))) void*)(Bg + (size_t)64 * ldb + k0),
            (__attribute__((address_space(3))) void*)(BsW + 2048), 16, 0, 0);
        __syncthreads();

        bf16x8 af[4], bfr[4];
        #pragma unroll
        for (int t = 0; t < 4; ++t) {
            af[t]  = *reinterpret_cast<const bf16x8*>(&As[(wm + t * 16 + lrow) * BK + quad * 8]);
            bfr[t] = *reinterpret_cast<const bf16x8*>(&Bs[(wn + t * 16 + lrow) * BK + quad * 8]);
        }
        #pragma unroll
        for (int mi = 0; mi < 4; ++mi)
            #pragma unroll
            for (int nj = 0; nj < 4; ++nj)
                acc[mi][nj] = __builtin_amdgcn_mfma_f32_16x16x32_bf16(
                    af[mi], bfr[nj], acc[mi][nj], 0, 0, 0);
    }

    // epilogue: C/D layout col = lane&15 (n), row = quad*4 + reg (m)
    float*  Cf = (float*)Cv;
    ushort* Cb = (ushort*)Cv;
    #pragma unroll
    for (int mi = 0; mi < 4; ++mi) {
        #pragma unroll
        for (int r = 0; r < 4; ++r) {
            const int m = m0 + wm + mi * 16 + quad * 4 + r;
            const float bm = (BMODE == BIAS_M) ? bias[m] : 0.0f;
            #pragma unroll
            for (int nj = 0; nj < 4; ++nj) {
                const int n = n0 + wn + nj * 16 + lrow;
                float v = acc[mi][nj][r] + ((BMODE == BIAS_N) ? bias[n] : bm);
                if (MASKED) v = mask[(size_t)n * LXc + m] ? v : -1000.0f;
                if (OUT_BF16) Cb[(size_t)m * ldc + n] = f2bf(v);
                else          Cf[(size_t)m * ldc + n] = v;
            }
        }
    }
}

// ---------------------------------------------------------------------------
// Transpose fp32 (R,C) -> bf16 (C,R)
// ---------------------------------------------------------------------------
__global__ __launch_bounds__(256)
void transpose_f32_bf16(const float* __restrict__ in, ushort* __restrict__ out,
                        int R, int C)
{
    __shared__ float tile[32][33];
    const int tx = threadIdx.x, ty = threadIdx.y;
    const int c0 = blockIdx.x * 32, r0 = blockIdx.y * 32;
    #pragma unroll
    for (int i = 0; i < 32; i += 8)
        tile[ty + i][tx] = in[(size_t)(r0 + ty + i) * C + c0 + tx];
    __syncthreads();
    #pragma unroll
    for (int i = 0; i < 32; i += 8)
        out[(size_t)(c0 + ty + i) * R + r0 + tx] = f2bf(tile[tx][ty + i]);
}

// ---------------------------------------------------------------------------
// Elementwise fp32 -> bf16 (n divisible by 4*256)
// ---------------------------------------------------------------------------
__global__ __launch_bounds__(256)
void convert_f32_bf16(const float* __restrict__ in, ushort* __restrict__ out, int n)
{
    const int i = (blockIdx.x * 256 + threadIdx.x) * 4;
    if (i < n) {
        float4 f = *reinterpret_cast<const float4*>(in + i);
        ushort4 u;
        u.x = f2bf(f.x); u.y = f2bf(f.y); u.z = f2bf(f.z); u.w = f2bf(f.w);
        *reinterpret_cast<ushort4*>(out + i) = u;
    }
}

// ---------------------------------------------------------------------------
// Row softmax on sT (LX rows x LZ fp32 cols); mask already applied (-1000).
// Scale by 1/32 then softmax over the row; write bf16 IN PLACE over the first
// half of the row's fp32 storage (attn row stride = 2*LZ ushorts).
// ---------------------------------------------------------------------------
__global__ __launch_bounds__(256)
void softmax_kernel(float* __restrict__ sT)
{
    const int x   = blockIdx.x;
    const int tid = threadIdx.x;
    float* row = sT + (size_t)x * LZc;
    ushort* orow = (ushort*)row;
    constexpr float scale = 1.0f / 32.0f;   // 1/sqrt(1024)

    float vals[LZc / 256];
    float mx = -1e30f;
    #pragma unroll
    for (int r = 0; r < LZc / 256; ++r) {
        float v = row[tid + r * 256] * scale;
        vals[r] = v;
        mx = fmaxf(mx, v);
    }
    __shared__ float redmax[4];
    #pragma unroll
    for (int off = 32; off > 0; off >>= 1)
        mx = fmaxf(mx, __shfl_down(mx, off, 64));
    if ((tid & 63) == 0) redmax[tid >> 6] = mx;
    __syncthreads();
    mx = fmaxf(fmaxf(redmax[0], redmax[1]), fmaxf(redmax[2], redmax[3]));

    float sum = 0.0f;
    #pragma unroll
    for (int r = 0; r < LZc / 256; ++r) {
        const float e = __expf(vals[r] - mx);
        vals[r] = e;
        sum += e;
    }
    __shared__ float redsum[4];
    #pragma unroll
    for (int off = 32; off > 0; off >>= 1)
        sum += __shfl_down(sum, off, 64);
    if ((tid & 63) == 0) redsum[tid >> 6] = sum;
    __syncthreads();
    sum = redsum[0] + redsum[1] + redsum[2] + redsum[3];
    const float inv = 1.0f / sum;

    #pragma unroll
    for (int r = 0; r < LZc / 256; ++r)
        orow[tid + r * 256] = f2bf(vals[r] * inv);
}

// ---------------------------------------------------------------------------
extern "C" void kernel_launch(void* const* d_in, const int* in_sizes, int n_in,
                              void* d_out, int out_size, void* d_ws, size_t ws_size,
                              hipStream_t stream)
{
    const float* X    = (const float*)d_in[0];   // (DX, LX)
    const float* Z    = (const float*)d_in[1];   // (DZ, LZ)
    const int*   mask = (const int*)  d_in[2];   // (LZ, LX)
    const float* Wq   = (const float*)d_in[3];   // (DA, DX)
    const float* bq   = (const float*)d_in[4];
    const float* Wk   = (const float*)d_in[5];   // (DA, DZ)
    const float* bk   = (const float*)d_in[6];
    const float* Wv   = (const float*)d_in[7];   // (DO, DZ)
    const float* bv   = (const float*)d_in[8];
    float* out = (float*)d_out;                  // (DO, LX) fp32

    // workspace layout (110 MB total)
    char* ws = (char*)d_ws;
    ushort* qT  = (ushort*)(ws);                   // (LX, DA) bf16   8 MB
    ushort* kT  = (ushort*)(ws + (8u  << 20));     // (LZ, DA) bf16   8 MB
    ushort* vB  = (ushort*)(ws + (16u << 20));     // (DO, LZ) bf16   8 MB
    float*  sT  = (float*) (ws + (24u << 20));     // (LX, LZ) fp32  64 MB
    ushort* XT  = (ushort*)(ws + (88u << 20));     // (LX, DX) bf16   8 MB
    ushort* ZT  = (ushort*)(ws + (96u << 20));     // (LZ, DZ) bf16   8 MB
    ushort* Wqb = (ushort*)(ws + (104u << 20));    // 2 MB
    ushort* Wkb = (ushort*)(ws + (106u << 20));    // 2 MB
    ushort* Wvb = (ushort*)(ws + (108u << 20));    // 2 MB

    const dim3 tb(32, 8);
    transpose_f32_bf16<<<dim3(LXc / 32, DXc / 32), tb, 0, stream>>>(X, XT, DXc, LXc);
    transpose_f32_bf16<<<dim3(LZc / 32, DZc / 32), tb, 0, stream>>>(Z, ZT, DZc, LZc);
    convert_f32_bf16<<<dim3(DAc * DXc / 1024), 256, 0, stream>>>(Wq, Wqb, DAc * DXc);
    convert_f32_bf16<<<dim3(DAc * DZc / 1024), 256, 0, stream>>>(Wk, Wkb, DAc * DZc);
    convert_f32_bf16<<<dim3(DOc * DZc / 1024), 256, 0, stream>>>(Wv, Wvb, DOc * DZc);

    // qT[x,d] = sum_c XT[x,c] Wq[d,c] + bq[d]   (M=LX, N=DA, K=DX)
    gemm_bt<BIAS_N, true, false><<<dim3(DAc / 128, LXc / 128), 256, 0, stream>>>(
        XT, Wqb, bq, nullptr, qT, LXc, DAc, DXc, DXc, DXc, DAc);
    // kT[z,d] = sum_c ZT[z,c] Wk[d,c] + bk[d]
    gemm_bt<BIAS_N, true, false><<<dim3(DAc / 128, LZc / 128), 256, 0, stream>>>(
        ZT, Wkb, bk, nullptr, kT, LZc, DAc, DZc, DZc, DZc, DAc);
    // v[o,z] = sum_c Wv[o,c] ZT[z,c] + bv[o]    (M=DO, N=LZ, K=DZ)
    gemm_bt<BIAS_M, true, false><<<dim3(LZc / 128, DOc / 128), 256, 0, stream>>>(
        Wvb, ZT, bv, nullptr, vB, DOc, LZc, DZc, DZc, DZc, LZc);

    // sT[x,z] = sum_d qT[x,d] kT[z,d], masked -> -1000   (M=LX, N=LZ, K=DA)
    gemm_bt<BIAS_NONE, false, true><<<dim3(LZc / 128, LXc / 128), 256, 0, stream>>>(
        qT, kT, nullptr, mask, sT, LXc, LZc, DAc, DAc, DAc, LZc);

    // masked scaled softmax over z; writes bf16 attn in place (row stride 2*LZ)
    softmax_kernel<<<dim3(LXc), 256, 0, stream>>>(sT);

    // out[o,x] = sum_z v[o,z] attnT[x,z]   (M=DO, N=LX, K=LZ; ldb = 2*LZ)
    gemm_bt<BIAS_NONE, false, false><<<dim3(LXc / 128, DOc / 128), 256, 0, stream>>>(
        vB, (ushort*)sT, nullptr, nullptr, out, DOc, LXc, LZc, LZc, 2 * LZc, LXc);
}

// Round 3
// 382.315 us; speedup vs baseline: 4.0625x; 1.0366x over previous
//
#include <hip/hip_runtime.h>
#include <hip/hip_bf16.h>
#include <math.h>

constexpr int DXc = 1024;
constexpr int DZc = 1024;
constexpr int LXc = 4096;
constexpr int LZc = 4096;
constexpr int DAc = 1024;   // DATTN
constexpr int DOc = 1024;   // DOUT

typedef __attribute__((ext_vector_type(8))) short bf16x8;   // 8 bf16 = 4 VGPRs
typedef __attribute__((ext_vector_type(4))) float f32x4;

__device__ __forceinline__ ushort f2bf(float f) {
    __hip_bfloat16 h = __float2bfloat16(f);
    return *reinterpret_cast<ushort*>(&h);
}
__device__ __forceinline__ float bflo(unsigned u) {   // low ushort -> float
    return __builtin_bit_cast(float, u << 16);
}
__device__ __forceinline__ float bfhi(unsigned u) {   // high ushort -> float
    return __builtin_bit_cast(float, u & 0xffff0000u);
}

enum BiasMode { BIAS_NONE, BIAS_M, BIAS_N };

// ---------------------------------------------------------------------------
// bf16 MFMA GEMM:  C[m,n] = sum_k A[m,k]*B[n,k]  (both operands K-major)
// Tile 128x128x32, 256 threads = 4 waves (2x2), each wave 64x64 via 4x4 MFMA
// tiles of 16x16x32. global_load_lds width=16 staging (contiguous lane-order
// LDS layout -- no padding).
// SPLIT: grid.z = #K-splits; K arg = K per split; writes fp32 partials to
//        Cv + z*M*ldc (no bias/mask).
// MASKED (score GEMM): C = mask[n*LX+m] ? v : -1000 before store.
// ---------------------------------------------------------------------------
template<BiasMode BMODE, bool OUT_BF16, bool MASKED, bool SPLIT>
__global__ __launch_bounds__(256)
void gemm_bt(const ushort* __restrict__ A, const ushort* __restrict__ B,
             const float* __restrict__ bias, const int* __restrict__ mask,
             void* __restrict__ Cv, int M, int N, int K,
             int lda, int ldb, int ldc)
{
    constexpr int BM = 128, BN = 128, BK = 32;
    __shared__ __align__(16) ushort As[BM * BK];   // 8 KB
    __shared__ __align__(16) ushort Bs[BN * BK];   // 8 KB

    const int tid = threadIdx.x;
    const int wv  = tid >> 6;
    const int wm  = (wv >> 1) * 64;
    const int wn  = (wv & 1) * 64;
    const int ln  = tid & 63;
    const int lrow = ln & 15;
    const int quad = ln >> 4;

    const int m0 = blockIdx.y * BM;
    const int n0 = blockIdx.x * BN;
    const int kbase = SPLIT ? blockIdx.z * K : 0;

    const int srow = tid >> 2;
    const int sseg = (tid & 3) * 8;
    const ushort* Ag = A + (size_t)(m0 + srow) * lda + sseg + kbase;
    const ushort* Bg = B + (size_t)(n0 + srow) * ldb + sseg + kbase;
    ushort* AsW = As + wv * 512;
    ushort* BsW = Bs + wv * 512;

    f32x4 acc[4][4] = {};

    for (int k0 = 0; k0 < K; k0 += BK) {
        __syncthreads();
        __builtin_amdgcn_global_load_lds(
            (const __attribute__((address_space(1))) void*)(Ag + k0),
            (__attribute__((address_space(3))) void*)(AsW), 16, 0, 0);
        __builtin_amdgcn_global_load_lds(
            (const __attribute__((address_space(1))) void*)(Ag + (size_t)64 * lda + k0),
            (__attribute__((address_space(3))) void*)(AsW + 2048), 16, 0, 0);
        __builtin_amdgcn_global_load_lds(
            (const __attribute__((address_space(1))) void*)(Bg + k0),
            (__attribute__((address_space(3))) void*)(BsW), 16, 0, 0);
        __builtin_amdgcn_global_load_lds(
            (const __attribute__((address_space(1))) void*)(Bg + (size_t)64 * ldb + k0),
            (__attribute__((address_space(3))) void*)(BsW + 2048), 16, 0, 0);
        __syncthreads();

        bf16x8 af[4], bfr[4];
        #pragma unroll
        for (int t = 0; t < 4; ++t) {
            af[t]  = *reinterpret_cast<const bf16x8*>(&As[(wm + t * 16 + lrow) * BK + quad * 8]);
            bfr[t] = *reinterpret_cast<const bf16x8*>(&Bs[(wn + t * 16 + lrow) * BK + quad * 8]);
        }
        #pragma unroll
        for (int mi = 0; mi < 4; ++mi)
            #pragma unroll
            for (int nj = 0; nj < 4; ++nj)
                acc[mi][nj] = __builtin_amdgcn_mfma_f32_16x16x32_bf16(
                    af[mi], bfr[nj], acc[mi][nj], 0, 0, 0);
    }

    // epilogue: C/D layout col = lane&15 (n), row = quad*4 + reg (m)
    float*  Cf = (float*)Cv + (SPLIT ? (size_t)blockIdx.z * M * ldc : 0);
    ushort* Cb = (ushort*)Cv;
    #pragma unroll
    for (int mi = 0; mi < 4; ++mi) {
        #pragma unroll
        for (int r = 0; r < 4; ++r) {
            const int m = m0 + wm + mi * 16 + quad * 4 + r;
            const float bm = (BMODE == BIAS_M) ? bias[m] : 0.0f;
            #pragma unroll
            for (int nj = 0; nj < 4; ++nj) {
                const int n = n0 + wn + nj * 16 + lrow;
                float v = acc[mi][nj][r] + ((BMODE == BIAS_N) ? bias[n] : bm);
                if (MASKED) v = mask[(size_t)n * LXc + m] ? v : -1000.0f;
                if (OUT_BF16) Cb[(size_t)m * ldc + n] = f2bf(v);
                else          Cf[(size_t)m * ldc + n] = v;
            }
        }
    }
}

// ---------------------------------------------------------------------------
// Sum KS fp32 partials (each M*ldc), add bias, write bf16 or fp32.
// ---------------------------------------------------------------------------
template<BiasMode BMODE, bool OUT_BF16>
__global__ __launch_bounds__(256)
void reduce_split(const float* __restrict__ P, const float* __restrict__ bias,
                  void* __restrict__ Cv, int M, int ldc, int KS)
{
    const size_t total = (size_t)M * ldc;
    const size_t i = ((size_t)blockIdx.x * 256 + threadIdx.x) * 4;
    if (i >= total) return;
    float4 s = *reinterpret_cast<const float4*>(P + i);
    for (int p = 1; p < KS; ++p) {
        const float4 t = *reinterpret_cast<const float4*>(P + (size_t)p * total + i);
        s.x += t.x; s.y += t.y; s.z += t.z; s.w += t.w;
    }
    if (BMODE == BIAS_N) {
        const float4 b = *reinterpret_cast<const float4*>(bias + (i % ldc));
        s.x += b.x; s.y += b.y; s.z += b.z; s.w += b.w;
    } else if (BMODE == BIAS_M) {
        const float b = bias[i / ldc];
        s.x += b; s.y += b; s.z += b; s.w += b;
    }
    if (OUT_BF16) {
        ushort4 u;
        u.x = f2bf(s.x); u.y = f2bf(s.y); u.z = f2bf(s.z); u.w = f2bf(s.w);
        *reinterpret_cast<ushort4*>((ushort*)Cv + i) = u;
    } else {
        *reinterpret_cast<float4*>((float*)Cv + i) = s;
    }
}

// ---------------------------------------------------------------------------
// Transpose fp32 (R,C) -> bf16 (C,R)
// ---------------------------------------------------------------------------
__global__ __launch_bounds__(256)
void transpose_f32_bf16(const float* __restrict__ in, ushort* __restrict__ out,
                        int R, int C)
{
    __shared__ float tile[32][33];
    const int tx = threadIdx.x, ty = threadIdx.y;
    const int c0 = blockIdx.x * 32, r0 = blockIdx.y * 32;
    #pragma unroll
    for (int i = 0; i < 32; i += 8)
        tile[ty + i][tx] = in[(size_t)(r0 + ty + i) * C + c0 + tx];
    __syncthreads();
    #pragma unroll
    for (int i = 0; i < 32; i += 8)
        out[(size_t)(c0 + ty + i) * R + r0 + tx] = f2bf(tile[tx][ty + i]);
}

__global__ __launch_bounds__(256)
void convert_f32_bf16(const float* __restrict__ in, ushort* __restrict__ out, int n)
{
    const int i = (blockIdx.x * 256 + threadIdx.x) * 4;
    if (i < n) {
        float4 f = *reinterpret_cast<const float4*>(in + i);
        ushort4 u;
        u.x = f2bf(f.x); u.y = f2bf(f.y); u.z = f2bf(f.z); u.w = f2bf(f.w);
        *reinterpret_cast<ushort4*>(out + i) = u;
    }
}

// ---------------------------------------------------------------------------
// Row softmax over bf16 sT (LX rows x LZ cols); masked entries hold -1000
// (exact in bf16). Scale 1/32, softmax over the row, write bf16 in place.
// ---------------------------------------------------------------------------
__global__ __launch_bounds__(256)
void softmax_kernel(ushort* __restrict__ sTb)
{
    const int x   = blockIdx.x;
    const int tid = threadIdx.x;
    ushort* row = sTb + (size_t)x * LZc;
    constexpr float scale = 1.0f / 32.0f;   // 1/sqrt(1024)

    float v[16];
    float mx = -1e30f;
    #pragma unroll
    for (int r = 0; r < 2; ++r) {
        const uint4 pk = *reinterpret_cast<const uint4*>(row + (size_t)(r * 256 + tid) * 8);
        const unsigned* w = reinterpret_cast<const unsigned*>(&pk);
        #pragma unroll
        for (int j = 0; j < 4; ++j) {
            const float lo = bflo(w[j]) * scale;
            const float hi = bfhi(w[j]) * scale;
            v[r * 8 + 2 * j]     = lo;
            v[r * 8 + 2 * j + 1] = hi;
            mx = fmaxf(mx, fmaxf(lo, hi));
        }
    }
    __shared__ float redmax[4];
    #pragma unroll
    for (int off = 32; off > 0; off >>= 1)
        mx = fmaxf(mx, __shfl_down(mx, off, 64));
    if ((tid & 63) == 0) redmax[tid >> 6] = mx;
    __syncthreads();
    mx = fmaxf(fmaxf(redmax[0], redmax[1]), fmaxf(redmax[2], redmax[3]));

    float sum = 0.0f;
    #pragma unroll
    for (int i = 0; i < 16; ++i) {
        v[i] = __expf(v[i] - mx);
        sum += v[i];
    }
    __shared__ float redsum[4];
    #pragma unroll
    for (int off = 32; off > 0; off >>= 1)
        sum += __shfl_down(sum, off, 64);
    if ((tid & 63) == 0) redsum[tid >> 6] = sum;
    __syncthreads();
    sum = redsum[0] + redsum[1] + redsum[2] + redsum[3];
    const float inv = 1.0f / sum;

    #pragma unroll
    for (int r = 0; r < 2; ++r) {
        uint4 pk;
        unsigned* w = reinterpret_cast<unsigned*>(&pk);
        #pragma unroll
        for (int j = 0; j < 4; ++j) {
            const unsigned lo = f2bf(v[r * 8 + 2 * j] * inv);
            const unsigned hi = f2bf(v[r * 8 + 2 * j + 1] * inv);
            w[j] = lo | (hi << 16);
        }
        *reinterpret_cast<uint4*>(row + (size_t)(r * 256 + tid) * 8) = pk;
    }
}

// ---------------------------------------------------------------------------
extern "C" void kernel_launch(void* const* d_in, const int* in_sizes, int n_in,
                              void* d_out, int out_size, void* d_ws, size_t ws_size,
                              hipStream_t stream)
{
    const float* X    = (const float*)d_in[0];   // (DX, LX)
    const float* Z    = (const float*)d_in[1];   // (DZ, LZ)
    const int*   mask = (const int*)  d_in[2];   // (LZ, LX)
    const float* Wq   = (const float*)d_in[3];   // (DA, DX)
    const float* bq   = (const float*)d_in[4];
    const float* Wk   = (const float*)d_in[5];   // (DA, DZ)
    const float* bk   = (const float*)d_in[6];
    const float* Wv   = (const float*)d_in[7];   // (DO, DZ)
    const float* bv   = (const float*)d_in[8];
    float* out = (float*)d_out;                  // (DO, LX) fp32

    // workspace layout
    char* ws = (char*)d_ws;
    ushort* XT  = (ushort*)(ws);                   // (LX, DX) bf16   8 MB
    ushort* ZT  = (ushort*)(ws + ( 8ull << 20));   // (LZ, DZ) bf16   8 MB
    ushort* Wqb = (ushort*)(ws + (16ull << 20));   // 2 MB
    ushort* Wkb = (ushort*)(ws + (18ull << 20));   // 2 MB
    ushort* Wvb = (ushort*)(ws + (20ull << 20));   // 2 MB
    ushort* qT  = (ushort*)(ws + (22ull << 20));   // (LX, DA) bf16   8 MB
    ushort* kT  = (ushort*)(ws + (30ull << 20));   // (LZ, DA) bf16   8 MB
    ushort* vB  = (ushort*)(ws + (38ull << 20));   // (DO, LZ) bf16   8 MB
    ushort* sTb = (ushort*)(ws + (46ull << 20));   // (LX, LZ) bf16  32 MB
    float*  P   = (float*) (ws + (78ull << 20));   // split-K partials

    const int KS_out = (ws_size >= (142ull << 20)) ? 4 : 2;   // 78 + KS*16 MB

    const dim3 tb(32, 8);
    transpose_f32_bf16<<<dim3(LXc / 32, DXc / 32), tb, 0, stream>>>(X, XT, DXc, LXc);
    transpose_f32_bf16<<<dim3(LZc / 32, DZc / 32), tb, 0, stream>>>(Z, ZT, DZc, LZc);
    convert_f32_bf16<<<dim3(DAc * DXc / 1024), 256, 0, stream>>>(Wq, Wqb, DAc * DXc);
    convert_f32_bf16<<<dim3(DAc * DZc / 1024), 256, 0, stream>>>(Wk, Wkb, DAc * DZc);
    convert_f32_bf16<<<dim3(DOc * DZc / 1024), 256, 0, stream>>>(Wv, Wvb, DOc * DZc);

    // qT[x,d] = sum_c XT[x,c] Wq[d,c]  (split-K=2) then +bq -> bf16
    gemm_bt<BIAS_NONE, false, false, true><<<dim3(DAc / 128, LXc / 128, 2), 256, 0, stream>>>(
        XT, Wqb, nullptr, nullptr, P, LXc, DAc, DXc / 2, DXc, DXc, DAc);
    reduce_split<BIAS_N, true><<<dim3(LXc * DAc / 1024), 256, 0, stream>>>(
        P, bq, qT, LXc, DAc, 2);

    // kT[z,d]
    gemm_bt<BIAS_NONE, false, false, true><<<dim3(DAc / 128, LZc / 128, 2), 256, 0, stream>>>(
        ZT, Wkb, nullptr, nullptr, P, LZc, DAc, DZc / 2, DZc, DZc, DAc);
    reduce_split<BIAS_N, true><<<dim3(LZc * DAc / 1024), 256, 0, stream>>>(
        P, bk, kT, LZc, DAc, 2);

    // v[o,z]
    gemm_bt<BIAS_NONE, false, false, true><<<dim3(LZc / 128, DOc / 128, 2), 256, 0, stream>>>(
        Wvb, ZT, nullptr, nullptr, P, DOc, LZc, DZc / 2, DZc, DZc, LZc);
    reduce_split<BIAS_M, true><<<dim3(DOc * LZc / 1024), 256, 0, stream>>>(
        P, bv, vB, DOc, LZc, 2);

    // sT[x,z] = sum_d qT[x,d] kT[z,d], masked -> -1000, bf16 out
    gemm_bt<BIAS_NONE, true, true, false><<<dim3(LZc / 128, LXc / 128), 256, 0, stream>>>(
        qT, kT, nullptr, mask, sTb, LXc, LZc, DAc, DAc, DAc, LZc);

    // scaled softmax over z, bf16 in place
    softmax_kernel<<<dim3(LXc), 256, 0, stream>>>(sTb);

    // out[o,x] = sum_z v[o,z] attnT[x,z]  (split-K) then fp32 out
    gemm_bt<BIAS_NONE, false, false, true><<<dim3(LXc / 128, DOc / 128, KS_out), 256, 0, stream>>>(
        vB, sTb, nullptr, nullptr, P, DOc, LXc, LZc / KS_out, LZc, LZc, LXc);
    reduce_split<BIAS_NONE, false><<<dim3(DOc * LXc / 1024), 256, 0, stream>>>(
        P, nullptr, out, DOc, LXc, KS_out);
}

// Round 4
// 311.948 us; speedup vs baseline: 4.9789x; 1.2256x over previous
//
#include <hip/hip_runtime.h>
#include <hip/hip_bf16.h>
#include <math.h>

constexpr int DXc = 1024;
constexpr int DZc = 1024;
constexpr int LXc = 4096;
constexpr int LZc = 4096;
constexpr int DAc = 1024;   // DATTN
constexpr int DOc = 1024;   // DOUT

typedef __attribute__((ext_vector_type(8))) short bf16x8;   // 8 bf16 = 4 VGPRs
typedef __attribute__((ext_vector_type(4))) float f32x4;

__device__ __forceinline__ ushort f2bf(float f) {
    __hip_bfloat16 h = __float2bfloat16(f);
    return *reinterpret_cast<ushort*>(&h);
}
__device__ __forceinline__ float bflo(unsigned u) {
    return __builtin_bit_cast(float, u << 16);
}
__device__ __forceinline__ float bfhi(unsigned u) {
    return __builtin_bit_cast(float, u & 0xffff0000u);
}

enum BiasMode { BIAS_NONE, BIAS_M, BIAS_N };

// ---------------------------------------------------------------------------
// bf16 MFMA GEMM tile body:  C[m,n] = sum_k A[m,k]*B[n,k]  (both K-major).
// 128x128x32 tile, 256 threads = 4 waves (2x2), each wave 64x64 via 4x4
// MFMA 16x16x32. global_load_lds width=16 staging, contiguous lane-order LDS.
// SPLIT: writes fp32 partial to Cv + zsplit*M*ldc (no bias).
// ---------------------------------------------------------------------------
template<BiasMode BMODE, bool OUT_BF16, bool SPLIT>
__device__ __forceinline__ void gemm_tile(
    const ushort* __restrict__ A, const ushort* __restrict__ B,
    const float* __restrict__ bias, void* __restrict__ Cv,
    int M, int N, int K, int lda, int ldb, int ldc,
    int m0, int n0, int kbase, int zsplit,
    ushort* As, ushort* Bs)
{
    constexpr int BK = 32;
    const int tid = threadIdx.x;
    const int wv  = tid >> 6;
    const int wm  = (wv >> 1) * 64;
    const int wn  = (wv & 1) * 64;
    const int ln  = tid & 63;
    const int lrow = ln & 15;
    const int quad = ln >> 4;

    const int srow = tid >> 2;
    const int sseg = (tid & 3) * 8;
    const ushort* Ag = A + (size_t)(m0 + srow) * lda + sseg + kbase;
    const ushort* Bg = B + (size_t)(n0 + srow) * ldb + sseg + kbase;
    ushort* AsW = As + wv * 512;
    ushort* BsW = Bs + wv * 512;

    f32x4 acc[4][4] = {};

    for (int k0 = 0; k0 < K; k0 += BK) {
        __syncthreads();
        __builtin_amdgcn_global_load_lds(
            (const __attribute__((address_space(1))) void*)(Ag + k0),
            (__attribute__((address_space(3))) void*)(AsW), 16, 0, 0);
        __builtin_amdgcn_global_load_lds(
            (const __attribute__((address_space(1))) void*)(Ag + (size_t)64 * lda + k0),
            (__attribute__((address_space(3))) void*)(AsW + 2048), 16, 0, 0);
        __builtin_amdgcn_global_load_lds(
            (const __attribute__((address_space(1))) void*)(Bg + k0),
            (__attribute__((address_space(3))) void*)(BsW), 16, 0, 0);
        __builtin_amdgcn_global_load_lds(
            (const __attribute__((address_space(1))) void*)(Bg + (size_t)64 * ldb + k0),
            (__attribute__((address_space(3))) void*)(BsW + 2048), 16, 0, 0);
        __syncthreads();

        bf16x8 af[4], bfr[4];
        #pragma unroll
        for (int t = 0; t < 4; ++t) {
            af[t]  = *reinterpret_cast<const bf16x8*>(&As[(wm + t * 16 + lrow) * BK + quad * 8]);
            bfr[t] = *reinterpret_cast<const bf16x8*>(&Bs[(wn + t * 16 + lrow) * BK + quad * 8]);
        }
        #pragma unroll
        for (int mi = 0; mi < 4; ++mi)
            #pragma unroll
            for (int nj = 0; nj < 4; ++nj)
                acc[mi][nj] = __builtin_amdgcn_mfma_f32_16x16x32_bf16(
                    af[mi], bfr[nj], acc[mi][nj], 0, 0, 0);
    }

    float*  Cf = (float*)Cv + (SPLIT ? (size_t)zsplit * M * ldc : 0);
    ushort* Cb = (ushort*)Cv;
    #pragma unroll
    for (int mi = 0; mi < 4; ++mi) {
        #pragma unroll
        for (int r = 0; r < 4; ++r) {
            const int m = m0 + wm + mi * 16 + quad * 4 + r;
            const float bm = (BMODE == BIAS_M) ? bias[m] : 0.0f;
            #pragma unroll
            for (int nj = 0; nj < 4; ++nj) {
                const int n = n0 + wn + nj * 16 + lrow;
                float v = acc[mi][nj][r] + ((BMODE == BIAS_N) ? bias[n] : bm);
                if (OUT_BF16) Cb[(size_t)m * ldc + n] = f2bf(v);
                else          Cf[(size_t)m * ldc + n] = v;
            }
        }
    }
}

// ---------------------------------------------------------------------------
// Batched projection GEMM: one dispatch for q, k, v (768 blocks).
//   b in [0,256):   qT[x,d] = sum_c XT[x,c] Wq[d,c] + bq[d]
//   b in [256,512): kT[z,d] = sum_c ZT[z,c] Wk[d,c] + bk[d]
//   b in [512,768): vB[o,z] = sum_c Wv[o,c] ZT[z,c] + bv[o]
// ---------------------------------------------------------------------------
__global__ __launch_bounds__(256)
void proj_kernel(const ushort* __restrict__ XT, const ushort* __restrict__ ZT,
                 const ushort* __restrict__ Wqb, const ushort* __restrict__ Wkb,
                 const ushort* __restrict__ Wvb,
                 const float* __restrict__ bq, const float* __restrict__ bk,
                 const float* __restrict__ bv,
                 ushort* __restrict__ qT, ushort* __restrict__ kT,
                 ushort* __restrict__ vB)
{
    __shared__ __align__(16) ushort As[128 * 32];
    __shared__ __align__(16) ushort Bs[128 * 32];
    int b = blockIdx.x;
    if (b < 256) {
        const int x = b & 7, y = b >> 3;
        gemm_tile<BIAS_N, true, false>(XT, Wqb, bq, qT, LXc, DAc, DXc,
                                       DXc, DXc, DAc, y * 128, x * 128, 0, 0, As, Bs);
    } else if (b < 512) {
        b -= 256;
        const int x = b & 7, y = b >> 3;
        gemm_tile<BIAS_N, true, false>(ZT, Wkb, bk, kT, LZc, DAc, DZc,
                                       DZc, DZc, DAc, y * 128, x * 128, 0, 0, As, Bs);
    } else {
        b -= 512;
        const int x = b & 31, y = b >> 5;
        gemm_tile<BIAS_M, true, false>(Wvb, ZT, bv, vB, DOc, LZc, DZc,
                                       DZc, DZc, LZc, y * 128, x * 128, 0, 0, As, Bs);
    }
}

// Score GEMM (pure): sTb[x,z] = sum_d qT[x,d] kT[z,d]  (bf16 out, no mask)
__global__ __launch_bounds__(256)
void score_kernel(const ushort* __restrict__ qT, const ushort* __restrict__ kT,
                  ushort* __restrict__ sTb)
{
    __shared__ __align__(16) ushort As[128 * 32];
    __shared__ __align__(16) ushort Bs[128 * 32];
    const int b = blockIdx.x;
    const int x = b & 31, y = b >> 5;
    gemm_tile<BIAS_NONE, true, false>(qT, kT, nullptr, sTb, LXc, LZc, DAc,
                                      DAc, DAc, LZc, y * 128, x * 128, 0, 0, As, Bs);
}

// Out GEMM split-K=4: P[z][o][x] partials fp32
__global__ __launch_bounds__(256)
void out_kernel(const ushort* __restrict__ vB, const ushort* __restrict__ sTb,
                float* __restrict__ P)
{
    __shared__ __align__(16) ushort As[128 * 32];
    __shared__ __align__(16) ushort Bs[128 * 32];
    gemm_tile<BIAS_NONE, false, true>(vB, sTb, nullptr, P, DOc, LXc, LZc / 4,
                                      LZc, LZc, LXc,
                                      blockIdx.y * 128, blockIdx.x * 128,
                                      blockIdx.z * (LZc / 4), blockIdx.z, As, Bs);
}

// ---------------------------------------------------------------------------
// Prep (one dispatch): X->XT bf16 transpose, Z->ZT, Wq/Wk/Wv fp32->bf16,
// mask (LZ,LX) int -> bitsT[x][z/32] packed transposed bitmask.
// ---------------------------------------------------------------------------
__global__ __launch_bounds__(256)
void prep_kernel(const float* __restrict__ X, const float* __restrict__ Z,
                 const float* __restrict__ Wq, const float* __restrict__ Wk,
                 const float* __restrict__ Wv, const int* __restrict__ mask,
                 ushort* __restrict__ XT, ushort* __restrict__ ZT,
                 ushort* __restrict__ Wqb, ushort* __restrict__ Wkb,
                 ushort* __restrict__ Wvb, unsigned* __restrict__ bits)
{
    __shared__ float tile[32][33];
    const int tid = threadIdx.x;
    int b = blockIdx.x;

    if (b < 8192) {   // two transposes, 4096 blocks each: (R=1024, C=4096)
        const float* in  = (b < 4096) ? X : Z;
        ushort*      out = (b < 4096) ? XT : ZT;
        const int local = b & 4095;
        const int bx = local & 127, by = local >> 7;     // C/32=128 tiles in x
        const int c0 = bx * 32, r0 = by * 32;
        const int tx = tid & 31, ty = tid >> 5;          // 32 x 8
        #pragma unroll
        for (int i = 0; i < 32; i += 8)
            tile[ty + i][tx] = in[(size_t)(r0 + ty + i) * LXc + c0 + tx];
        __syncthreads();
        #pragma unroll
        for (int i = 0; i < 32; i += 8)
            out[(size_t)(c0 + ty + i) * DXc + r0 + tx] = f2bf(tile[tx][ty + i]);
        return;
    }
    if (b < 11264) {  // three weight converts, 1024 blocks each (1M elems)
        b -= 8192;
        const float* in  = (b < 1024) ? Wq : (b < 2048) ? Wk : Wv;
        ushort*      out = (b < 1024) ? Wqb : (b < 2048) ? Wkb : Wvb;
        const int local = b & 1023;
        const size_t i = ((size_t)local * 256 + tid) * 4;
        float4 f = *reinterpret_cast<const float4*>(in + i);
        ushort4 u;
        u.x = f2bf(f.x); u.y = f2bf(f.y); u.z = f2bf(f.z); u.w = f2bf(f.w);
        *reinterpret_cast<ushort4*>(out + i) = u;
        return;
    }
    // mask pack: 2048 blocks; block = (xb in [0,16), zb in [0,128))
    b -= 11264;
    const int xb = b & 15, zb = b >> 4;
    const int x  = xb * 256 + tid;
    const int z0 = zb * 32;
    unsigned w = 0;
    #pragma unroll 8
    for (int i = 0; i < 32; ++i)
        w |= (mask[(size_t)(z0 + i) * LXc + x] != 0 ? 1u : 0u) << i;
    bits[(size_t)x * (LZc / 32) + zb] = w;
}

// ---------------------------------------------------------------------------
// Row softmax over bf16 sTb (LX x LZ) with packed mask bits; scale 1/32,
// masked -> -1000/32; softmax over the row; bf16 in place.
// ---------------------------------------------------------------------------
__global__ __launch_bounds__(256)
void softmax_kernel(ushort* __restrict__ sTb, const unsigned* __restrict__ bits)
{
    const int x   = blockIdx.x;
    const int tid = threadIdx.x;
    ushort* row = sTb + (size_t)x * LZc;
    constexpr float scale = 1.0f / 32.0f;   // 1/sqrt(1024)
    constexpr float MASKV = -1000.0f / 32.0f;

    float v[16];
    float mx = -1e30f;
    #pragma unroll
    for (int r = 0; r < 2; ++r) {
        const uint4 pk = *reinterpret_cast<const uint4*>(row + (size_t)(r * 256 + tid) * 8);
        const unsigned* w = reinterpret_cast<const unsigned*>(&pk);
        const unsigned mb = (bits[(size_t)x * 128 + r * 64 + (tid >> 2)] >> ((tid & 3) * 8)) & 0xffu;
        #pragma unroll
        for (int j = 0; j < 4; ++j) {
            const float lo = ((mb >> (2 * j))     & 1u) ? bflo(w[j]) * scale : MASKV;
            const float hi = ((mb >> (2 * j + 1)) & 1u) ? bfhi(w[j]) * scale : MASKV;
            v[r * 8 + 2 * j]     = lo;
            v[r * 8 + 2 * j + 1] = hi;
            mx = fmaxf(mx, fmaxf(lo, hi));
        }
    }
    __shared__ float redmax[4];
    #pragma unroll
    for (int off = 32; off > 0; off >>= 1)
        mx = fmaxf(mx, __shfl_down(mx, off, 64));
    if ((tid & 63) == 0) redmax[tid >> 6] = mx;
    __syncthreads();
    mx = fmaxf(fmaxf(redmax[0], redmax[1]), fmaxf(redmax[2], redmax[3]));

    float sum = 0.0f;
    #pragma unroll
    for (int i = 0; i < 16; ++i) {
        v[i] = __expf(v[i] - mx);
        sum += v[i];
    }
    __shared__ float redsum[4];
    #pragma unroll
    for (int off = 32; off > 0; off >>= 1)
        sum += __shfl_down(sum, off, 64);
    if ((tid & 63) == 0) redsum[tid >> 6] = sum;
    __syncthreads();
    sum = redsum[0] + redsum[1] + redsum[2] + redsum[3];
    const float inv = 1.0f / sum;

    #pragma unroll
    for (int r = 0; r < 2; ++r) {
        uint4 pk;
        unsigned* w = reinterpret_cast<unsigned*>(&pk);
        #pragma unroll
        for (int j = 0; j < 4; ++j) {
            const unsigned lo = f2bf(v[r * 8 + 2 * j] * inv);
            const unsigned hi = f2bf(v[r * 8 + 2 * j + 1] * inv);
            w[j] = lo | (hi << 16);
        }
        *reinterpret_cast<uint4*>(row + (size_t)(r * 256 + tid) * 8) = pk;
    }
}

// Sum 4 fp32 partials -> fp32 out
__global__ __launch_bounds__(256)
void reduce_kernel(const float* __restrict__ P, float* __restrict__ out)
{
    constexpr size_t total = (size_t)DOc * LXc;
    const size_t i = ((size_t)blockIdx.x * 256 + threadIdx.x) * 4;
    float4 s = *reinterpret_cast<const float4*>(P + i);
    #pragma unroll
    for (int p = 1; p < 4; ++p) {
        const float4 t = *reinterpret_cast<const float4*>(P + (size_t)p * total + i);
        s.x += t.x; s.y += t.y; s.z += t.z; s.w += t.w;
    }
    *reinterpret_cast<float4*>(out + i) = s;
}

// ---------------------------------------------------------------------------
extern "C" void kernel_launch(void* const* d_in, const int* in_sizes, int n_in,
                              void* d_out, int out_size, void* d_ws, size_t ws_size,
                              hipStream_t stream)
{
    const float* X    = (const float*)d_in[0];
    const float* Z    = (const float*)d_in[1];
    const int*   mask = (const int*)  d_in[2];
    const float* Wq   = (const float*)d_in[3];
    const float* bq   = (const float*)d_in[4];
    const float* Wk   = (const float*)d_in[5];
    const float* bk   = (const float*)d_in[6];
    const float* Wv   = (const float*)d_in[7];
    const float* bv   = (const float*)d_in[8];
    float* out = (float*)d_out;

    // ws layout (106 MB). P (64 MB at offset 0) OVERLAYS XT/ZT/W/qT/kT --
    // all dead by the time the out GEMM writes P.
    char* ws = (char*)d_ws;
    ushort*   XT   = (ushort*)(ws);                   // 8 MB   [dead after proj]
    ushort*   ZT   = (ushort*)(ws + ( 8ull << 20));   // 8 MB   [dead after proj]
    ushort*   Wqb  = (ushort*)(ws + (16ull << 20));   // 2 MB   [dead after proj]
    ushort*   Wkb  = (ushort*)(ws + (18ull << 20));   // 2 MB   [dead after proj]
    ushort*   Wvb  = (ushort*)(ws + (20ull << 20));   // 2 MB   [dead after proj]
    ushort*   qT   = (ushort*)(ws + (22ull << 20));   // 8 MB   [dead after score]
    ushort*   kT   = (ushort*)(ws + (30ull << 20));   // 8 MB   [dead after score]
    float*    P    = (float*) (ws);                   // 64 MB  [out partials]
    ushort*   vB   = (ushort*)(ws + (64ull << 20));   // 8 MB
    ushort*   sTb  = (ushort*)(ws + (72ull << 20));   // 32 MB
    unsigned* bits = (unsigned*)(ws + (104ull << 20));// 2 MB

    prep_kernel<<<dim3(13312), 256, 0, stream>>>(X, Z, Wq, Wk, Wv, mask,
                                                 XT, ZT, Wqb, Wkb, Wvb, bits);
    proj_kernel<<<dim3(768), 256, 0, stream>>>(XT, ZT, Wqb, Wkb, Wvb,
                                               bq, bk, bv, qT, kT, vB);
    score_kernel<<<dim3(1024), 256, 0, stream>>>(qT, kT, sTb);
    softmax_kernel<<<dim3(LXc), 256, 0, stream>>>(sTb, bits);
    out_kernel<<<dim3(32, 8, 4), 256, 0, stream>>>(vB, sTb, P);
    reduce_kernel<<<dim3(DOc * LXc / 1024), 256, 0, stream>>>(P, out);
}